// Round 7
// baseline (315.586 us; speedup 1.0000x reference)
//
#include <hip/hip_runtime.h>

#define T_DIM 4000
#define B_DIM 64
#define C_DIM 64
#define U_DIM 200
#define LOG2E 1.4426950408889634f
#define LN2 0.6931471805599453f

#define PAIRS 2000                 // t-pairs (1,2),(3,4),...,(3999,pad)
#define PB_BYTES (PAIRS * 800)     // 1.6 MB per batch: 800 B per pair (50 lanes x 16 B)
#define NSLOT 25                   // uint4 slots in scan: 50 steps in flight
#define RPB 16                     // pairs per prep block (32 t-rows)
#define MBLK (PAIRS / RPB)         // 125 prep blocks per batch

__device__ __forceinline__ float hw_exp2(float x) { return __builtin_amdgcn_exp2f(x); }
__device__ __forceinline__ float hw_log2(float x) { return __builtin_amdgcn_logf(x); }

// DPP: zero-fill (bound_ctrl) lane permute, pure VALU (no DS pipe). 0x138 = wave_shr:1.
template <int CTRL>
__device__ __forceinline__ int dpp_i(int x) {
    return __builtin_amdgcn_update_dpp(0, x, CTRL, 0xF, 0xF, true);
}
template <int CTRL>
__device__ __forceinline__ float dpp_f(float x) {
    return __uint_as_float((unsigned)dpp_i<CTRL>((int)__float_as_uint(x)));
}

__device__ __forceinline__ unsigned rne_bf16(float v) {   // RNE-rounded bf16 in hi16
    unsigned b = __float_as_uint(v);
    return b + 0x7FFFu + ((b >> 16) & 1u);
}

// ---------------- prep: fused gather-exp (via LDS, no divergent global gathers) + lse ----------------
// Block = (b, m): stages rows t = 32m+1 .. 32m+32 of batch b into LDS as exp2 values,
// emits Eg pairs tp = 16m..16m+15 (layout: b*PB_BYTES + tp*800 + l*16, bf16 x8), and
// accumulates this block's share of the log-softmax normalizer sum_t lse(t,b).
__global__ __launch_bounds__(256) void prep_kernel(const float* __restrict__ in,
                                                   const int* __restrict__ tgt,
                                                   unsigned* __restrict__ eg,
                                                   float* __restrict__ out) {
    __shared__ float ex[32 * 64];      // exp2 of 32 staged rows
    __shared__ float rowsum[34];       // [0..31] row sums; [33] = row t=0 (m==0 only)
    __shared__ int4 tgl[50];
    const int tid = threadIdx.x;
    const int m = blockIdx.x % MBLK;
    const int b = blockIdx.x / MBLK;
    const int tbase = m * 32;

    if (tid < 34) rowsum[tid] = 0.0f;
    if (tid < 50) tgl[tid] = ((const int4*)(tgt + b * U_DIM))[tid];
    __syncthreads();

    // stage 32 rows, coalesced float4, exp2 on the fly
    #pragma unroll
    for (int it = 0; it < 2; ++it) {
        int idx = tid + it * 256;              // 0..511
        int r = idx >> 4, q = idx & 15;
        int t = tbase + 1 + r;
        if (t > T_DIM - 1) t = T_DIM - 1;      // last block's pad half (never consumed)
        float4 v = *(const float4*)(in + (size_t)t * 4096 + b * 64 + q * 4);
        float4 e;
        e.x = hw_exp2(v.x * LOG2E); e.y = hw_exp2(v.y * LOG2E);
        e.z = hw_exp2(v.z * LOG2E); e.w = hw_exp2(v.w * LOG2E);
        *(float4*)&ex[r * 64 + q * 4] = e;
    }
    // row t=0 contributes to lse only (not covered by the pair enumeration)
    if (m == 0 && tid < 16) {
        float4 v = *(const float4*)(in + b * 64 + tid * 4);
        atomicAdd(&rowsum[33], hw_exp2(v.x * LOG2E) + hw_exp2(v.y * LOG2E)
                             + hw_exp2(v.z * LOG2E) + hw_exp2(v.w * LOG2E));
    }
    __syncthreads();

    // row sums: 8 threads per row, shfl-reduce within the 8-lane group (no atomics)
    {
        int r = tid >> 3, seg = tid & 7;
        const float4* p = (const float4*)&ex[r * 64 + seg * 8];
        float4 a = p[0], c = p[1];
        float s = (a.x + a.y + a.z + a.w) + (c.x + c.y + c.z + c.w);
        s += __shfl_xor(s, 1);
        s += __shfl_xor(s, 2);
        s += __shfl_xor(s, 4);
        if (seg == 0) rowsum[r] = s;
    }

    // emit Eg: 16 pairs x 50 lanes, gathered from LDS (random-bank, ~2-way = free)
    for (int o = tid; o < 800; o += 256) {
        int tp_l = o / 50, l = o - tp_l * 50;
        int4 tg = tgl[l];
        int r0 = tp_l * 128;                   // local row 2*tp_l
        int r1 = r0 + 64;
        float e0 = ex[r0 + (tg.x & 63)], e1 = ex[r0 + (tg.y & 63)];
        float e2 = ex[r0 + (tg.z & 63)], e3 = ex[r0 + (tg.w & 63)];
        float f0 = ex[r1 + (tg.x & 63)], f1 = ex[r1 + (tg.y & 63)];
        float f2 = ex[r1 + (tg.z & 63)], f3 = ex[r1 + (tg.w & 63)];
        uint4 w;
        w.x = (rne_bf16(e0) >> 16) | (rne_bf16(e1) & 0xFFFF0000u);
        w.y = (rne_bf16(e2) >> 16) | (rne_bf16(e3) & 0xFFFF0000u);
        w.z = (rne_bf16(f0) >> 16) | (rne_bf16(f1) & 0xFFFF0000u);
        w.w = (rne_bf16(f2) >> 16) | (rne_bf16(f3) & 0xFFFF0000u);
        *(uint4*)((char*)eg + (size_t)b * PB_BYTES + (size_t)(m * RPB + tp_l) * 800 + l * 16) = w;
    }
    __syncthreads();

    // lse contribution: rows tbase+1..tbase+32 (skip t=4000), plus row 0 for m==0
    if (tid < 64) {
        float val = 0.0f;
        if (tid < 32 && tbase + 1 + tid <= T_DIM - 1) val = hw_log2(rowsum[tid]);
        if (tid == 33 && m == 0) val = hw_log2(rowsum[33]);
        #pragma unroll
        for (int o = 32; o > 0; o >>= 1) val += __shfl_xor(val, o);
        if (tid == 0) atomicAdd(out, val * (LN2 / 64.0f));
    }
}

// ---- per-lane-scaled linear-domain scan core (R5/R6-proven, absmax 0.0) ----
struct ScanState { float A0, A1, A2, A3; int S, D; };

__device__ __forceinline__ void renorm(ScanState& st, int lane) {
    float m = fmaxf(fmaxf(st.A0, st.A1), fmaxf(st.A2, st.A3));
    int e = (int)((__float_as_uint(m) >> 23) & 0xFFu);
    int cand = st.S + e - 127;
    int snb = dpp_i<0x138>(st.S);
    if (lane == 0) snb = -(1 << 28);
    int snew = max(cand, snb);
    int k = st.S - snew;
    st.A0 = ldexpf(st.A0, k);
    st.A1 = ldexpf(st.A1, k);
    st.A2 = ldexpf(st.A2, k);
    st.A3 = ldexpf(st.A3, k);
    st.S = snew;
    int d = dpp_i<0x138>(snew) - snew;
    st.D = min(d, 60);
}

__device__ __forceinline__ void step(ScanState& st, float e0, float e1, float e2, float e3) {
    float sh = ldexpf(dpp_f<0x138>(st.A3), st.D);
    sh = fminf(sh, 1.125899906842624e15f);         // 2^50; fminf absorbs inf
    float t0 = st.A0 + sh;
    float t1 = st.A1 + st.A0;
    float t2 = st.A2 + st.A1;
    float t3 = st.A3 + st.A2;
    st.A0 = e0 * t0; st.A1 = e1 * t1; st.A2 = e2 * t2; st.A3 = e3 * t3;
}

__device__ __forceinline__ ScanState scan_init(const float* in, const int* tgt, int lane, int b) {
    float v0 = in[b * 64 + (tgt[b * U_DIM] & 63)];
    ScanState st;
    st.A0 = (lane == 0) ? hw_exp2(v0 * LOG2E) : 0.0f;
    st.A1 = 0.0f; st.A2 = 0.0f; st.A3 = 0.0f;
    st.S = 0; st.D = 0;
    return st;
}

__device__ __forceinline__ void scan_finish(const ScanState& st, int lane, float* out) {
    if (lane == 49) {
        float a2 = hw_log2(fmaxf(st.A3, 1e-38f)) + (float)st.S;
        atomicAdd(out, -a2 * (LN2 / 64.0f));
    }
}

#define LO(x) __uint_as_float((x) << 16)
#define HI(x) __uint_as_float((x) & 0xFFFF0000u)

// Standalone scan: one wave per batch, NSLOT=25 deep pipeline. launch_bounds(64,1)
// gives the register allocator room to keep all 25 uint4 slots live (~130 VGPR) —
// occupancy is irrelevant at 64 total waves on 1024 SIMDs.
__global__ __launch_bounds__(64, 1) void scan_kernel(const float* __restrict__ in,
                                                     const int* __restrict__ tgt,
                                                     const unsigned* __restrict__ eg,
                                                     float* __restrict__ out) {
    const int lane = threadIdx.x;
    const int b = blockIdx.x;
    const int lidx = (lane < 50) ? lane : 49;      // junk lanes flow right only
    ScanState st = scan_init(in, tgt, lane, b);

    const char* egb = (const char*)eg + (size_t)b * PB_BYTES;
    int off = lidx * 16;                           // pair 0 (t=1,2)
    uint4 wb[NSLOT];
    #pragma unroll
    for (int j = 0; j < NSLOT; ++j) { wb[j] = *(const uint4*)(egb + off); off += 800; }

    for (int k = 0; k < 79; ++k) {                 // pairs 0..1974 (t = 1..3950)
        #pragma unroll
        for (int j = 0; j < NSLOT; ++j) {
            if ((j & 3) == 0) renorm(st, lane);    // every <=8 steps
            uint4 w = wb[j];
            wb[j] = *(const uint4*)(egb + off); off += 800;   // refills end at pair 1999
            step(st, LO(w.x), HI(w.x), LO(w.y), HI(w.y));
            step(st, LO(w.z), HI(w.z), LO(w.w), HI(w.w));
        }
    }
    #pragma unroll                                  // pairs 1975..1998 (t = 3951..3998)
    for (int j = 0; j < NSLOT - 1; ++j) {
        if ((j & 3) == 0) renorm(st, lane);
        uint4 w = wb[j];
        step(st, LO(w.x), HI(w.x), LO(w.y), HI(w.y));
        step(st, LO(w.z), HI(w.z), LO(w.w), HI(w.w));
    }
    {                                               // pair 1999: first half only (t = 3999)
        uint4 w = wb[NSLOT - 1];
        step(st, LO(w.x), HI(w.x), LO(w.y), HI(w.y));
    }
    scan_finish(st, lane, out);
}

// ---- fallback pair (no-workspace path, R6 structure) ----
__global__ __launch_bounds__(256) void lse_sum_kernel(const float* __restrict__ in,
                                                      float* __restrict__ out) {
    const int lane = threadIdx.x & 63;
    const int w = threadIdx.x >> 6;
    const int wid = blockIdx.x * 4 + w;
    const int ROWS = (T_DIM * B_DIM) / 1024;
    const float* p = in + (size_t)wid * ROWS * 64 + lane;
    float acc = 0.0f;
    for (int i = 0; i < ROWS; i += 2) {
        float xa = p[(size_t)i * 64];
        float xb = p[(size_t)(i + 1) * 64];
        float ea = hw_exp2(xa * LOG2E);
        float eb = hw_exp2(xb * LOG2E);
        #pragma unroll
        for (int off = 32; off > 0; off >>= 1) {
            ea += __shfl_xor(ea, off);
            eb += __shfl_xor(eb, off);
        }
        acc += hw_log2(ea) + hw_log2(eb);
    }
    __shared__ float red[4];
    if (lane == 0) red[w] = acc;
    __syncthreads();
    if (threadIdx.x == 0)
        atomicAdd(out, (red[0] + red[1] + red[2] + red[3]) * (LN2 / 64.0f));
}

__global__ __launch_bounds__(64) void scan_fb(const float* __restrict__ in,
                                              const int* __restrict__ tgt,
                                              float* __restrict__ out) {
    const int lane = threadIdx.x;
    const int b = blockIdx.x;
    const int lidx = (lane < 50) ? lane : 49;
    int4 tg = ((const int4*)(tgt + b * U_DIM))[lidx];
    tg.x &= 63; tg.y &= 63; tg.z &= 63; tg.w &= 63;
    ScanState st = scan_init(in, tgt, lane, b);
    const char* inb = (const char*)in;
    int o0 = 16384 + b * 256 + tg.x * 4;
    int o1 = 16384 + b * 256 + tg.y * 4;
    int o2 = 16384 + b * 256 + tg.z * 4;
    int o3 = 16384 + b * 256 + tg.w * 4;
    const int m0 = 3999 * 16384 + b * 256 + tg.x * 4;
    const int m1 = m0 + (tg.y - tg.x) * 4;
    const int m2 = m0 + (tg.z - tg.x) * 4;
    const int m3 = m0 + (tg.w - tg.x) * 4;
    float f0[16], f1[16], f2[16], f3[16];
    #pragma unroll
    for (int j = 0; j < 16; ++j) {
        f0[j] = *(const float*)(inb + min(o0, m0)); o0 += 16384;
        f1[j] = *(const float*)(inb + min(o1, m1)); o1 += 16384;
        f2[j] = *(const float*)(inb + min(o2, m2)); o2 += 16384;
        f3[j] = *(const float*)(inb + min(o3, m3)); o3 += 16384;
    }
    for (int k = 0; k < 249; ++k) {
        #pragma unroll
        for (int j = 0; j < 16; ++j) {
            if (j == 0 || j == 8) renorm(st, lane);
            float e0 = hw_exp2(f0[j] * LOG2E);
            float e1 = hw_exp2(f1[j] * LOG2E);
            float e2 = hw_exp2(f2[j] * LOG2E);
            float e3 = hw_exp2(f3[j] * LOG2E);
            f0[j] = *(const float*)(inb + min(o0, m0)); o0 += 16384;
            f1[j] = *(const float*)(inb + min(o1, m1)); o1 += 16384;
            f2[j] = *(const float*)(inb + min(o2, m2)); o2 += 16384;
            f3[j] = *(const float*)(inb + min(o3, m3)); o3 += 16384;
            step(st, e0, e1, e2, e3);
        }
    }
    #pragma unroll
    for (int j = 0; j < 15; ++j) {
        if (j == 0 || j == 8) renorm(st, lane);
        float e0 = hw_exp2(f0[j] * LOG2E);
        float e1 = hw_exp2(f1[j] * LOG2E);
        float e2 = hw_exp2(f2[j] * LOG2E);
        float e3 = hw_exp2(f3[j] * LOG2E);
        step(st, e0, e1, e2, e3);
    }
    scan_finish(st, lane, out);
}

extern "C" void kernel_launch(void* const* d_in, const int* in_sizes, int n_in,
                              void* d_out, int out_size, void* d_ws, size_t ws_size,
                              hipStream_t stream) {
    const float* inputs = (const float*)d_in[0];   // (T, B, C) fp32
    const int* targets = (const int*)d_in[1];      // (B, U) int32
    float* out = (float*)d_out;                    // scalar fp32

    (void)hipMemsetAsync(out, 0, sizeof(float), stream);

    const size_t eg_bytes = (size_t)B_DIM * PB_BYTES;   // 102.4 MB
    if (ws_size >= eg_bytes) {
        unsigned* eg = (unsigned*)d_ws;
        prep_kernel<<<B_DIM * MBLK, 256, 0, stream>>>(inputs, targets, eg, out);
        scan_kernel<<<B_DIM, 64, 0, stream>>>(inputs, targets, eg, out);
    } else {
        scan_fb<<<B_DIM, 64, 0, stream>>>(inputs, targets, out);
        lse_sum_kernel<<<256, 256, 0, stream>>>(inputs, out);
    }
}

// Round 8
// 188.984 us; speedup vs baseline: 1.6699x; 1.6699x over previous
//
#include <hip/hip_runtime.h>

#define T_DIM 4000
#define B_DIM 64
#define C_DIM 64
#define U_DIM 200
#define LOG2E 1.4426950408889634f
#define LN2 0.6931471805599453f

#define PAIRS 2000                 // pair tp = (t=2tp, t=2tp+1); no pad row
#define PB_BYTES (PAIRS * 800)     // 1.6 MB per batch (50 lanes x 16 B per pair)
#define NSLOT 20                   // uint4 slots per scan wave: 40 steps in flight

__device__ __forceinline__ float hw_exp2(float x) { return __builtin_amdgcn_exp2f(x); }
__device__ __forceinline__ float hw_log2(float x) { return __builtin_amdgcn_logf(x); }

// DPP: zero-fill (bound_ctrl) lane permute, pure VALU. 0x138=wave_shr:1 (lane l <- l-1),
// 0x130=wave_shl:1 (lane l <- l+1).
template <int CTRL>
__device__ __forceinline__ int dpp_i(int x) {
    return __builtin_amdgcn_update_dpp(0, x, CTRL, 0xF, 0xF, true);
}
template <int CTRL>
__device__ __forceinline__ float dpp_f(float x) {
    return __uint_as_float((unsigned)dpp_i<CTRL>((int)__float_as_uint(x)));
}

__device__ __forceinline__ unsigned rne_bf16(float v) {   // RNE bf16 in hi16
    unsigned b = __float_as_uint(v);
    return b + 0x7FFFu + ((b >> 16) & 1u);
}

// ---------------- prep: coalesced stage -> LDS exp2 tile -> Eg emit + row-lse ----------------
// Block = (bg 0..7, tc 0..249): batches 8bg..8bg+7, rows t = 16tc..16tc+15 = pairs 8tc..8tc+7.
__global__ __launch_bounds__(256) void prep_kernel(const float* __restrict__ in,
                                                   const int* __restrict__ tgt,
                                                   unsigned* __restrict__ eg,
                                                   float* __restrict__ out) {
    __shared__ float ex[16 * 8 * 68];   // 68-stride pad (16B-aligned rows, spread banks)
    __shared__ unsigned tgc[400];       // uchar4-packed targets for 8 batches
    __shared__ float red[4];
    const int tid = threadIdx.x;
    const int bg = blockIdx.x & 7;
    const int tc = blockIdx.x >> 3;
    const int t0 = tc * 16, b0 = bg * 8;

    // stage targets (each uint = 4 consecutive u's of one batch)
    for (int o = tid; o < 400; o += 256) {
        int4 tv = ((const int4*)tgt)[bg * 400 + o];
        tgc[o] = (unsigned)(tv.x & 63) | ((unsigned)(tv.y & 63) << 8)
               | ((unsigned)(tv.z & 63) << 16) | ((unsigned)(tv.w & 63) << 24);
    }
    // stage 16 t x 8 b x 64 c, coalesced float4, exp2 in flight
    #pragma unroll
    for (int k = 0; k < 8; ++k) {
        int flat = k * 256 + tid;              // 0..2047
        int t_l = flat >> 7, i = flat & 127, b_l = i >> 4, q = i & 15;
        float4 v = *(const float4*)(in + (size_t)(t0 + t_l) * 4096 + (b0 + b_l) * 64 + q * 4);
        float4 e;
        e.x = hw_exp2(v.x * LOG2E); e.y = hw_exp2(v.y * LOG2E);
        e.z = hw_exp2(v.z * LOG2E); e.w = hw_exp2(v.w * LOG2E);
        *(float4*)&ex[(t_l * 8 + b_l) * 68 + q * 4] = e;
    }
    __syncthreads();

    // row-lse: threads 0..127 each own one (t,b) row; covers every t (incl. t=0)
    {
        float v = 0.0f;
        if (tid < 128) {
            const float4* p = (const float4*)&ex[tid * 68];
            float s = 0.0f;
            #pragma unroll
            for (int j = 0; j < 16; ++j) { float4 a = p[j]; s += (a.x + a.y) + (a.z + a.w); }
            v = hw_log2(s);
        }
        #pragma unroll
        for (int o = 32; o > 0; o >>= 1) v += __shfl_xor(v, o);
        if ((tid & 63) == 0) red[tid >> 6] = v;
    }

    // emit: 8 pairs x 8 b x 50 l = 3200 uint4; coalesced stores, LDS gathers
    for (int it = 0; it < 13; ++it) {
        int o = it * 256 + tid;
        if (o < 3200) {
            int l = o % 50;
            int rest = o / 50;                 // 0..63
            int b_l = rest & 7, tp_l = rest >> 3;
            unsigned tw = tgc[b_l * 50 + l];
            int c0 = tw & 255, c1 = (tw >> 8) & 255, c2 = (tw >> 16) & 255, c3 = tw >> 24;
            const float* plo = &ex[(tp_l * 16 + b_l) * 68];   // t = 2*tp_l (local)
            const float* phi = plo + 8 * 68;                  // t = 2*tp_l + 1
            uint4 w;
            w.x = (rne_bf16(plo[c0]) >> 16) | (rne_bf16(plo[c1]) & 0xFFFF0000u);
            w.y = (rne_bf16(plo[c2]) >> 16) | (rne_bf16(plo[c3]) & 0xFFFF0000u);
            w.z = (rne_bf16(phi[c0]) >> 16) | (rne_bf16(phi[c1]) & 0xFFFF0000u);
            w.w = (rne_bf16(phi[c2]) >> 16) | (rne_bf16(phi[c3]) & 0xFFFF0000u);
            *(uint4*)((char*)eg + (size_t)(b0 + b_l) * PB_BYTES
                      + (size_t)(tc * 8 + tp_l) * 800 + l * 16) = w;
        }
    }
    __syncthreads();
    if (tid == 0)
        atomicAdd(out, (red[0] + red[1] + red[2] + red[3]) * (LN2 / 64.0f));
}

// ---- forward scan core (R5/R6/R7-proven, absmax 0.0) ----
struct ScanState { float A0, A1, A2, A3; int S, D; };

__device__ __forceinline__ void renorm(ScanState& st, int lane) {
    float m = fmaxf(fmaxf(st.A0, st.A1), fmaxf(st.A2, st.A3));
    int e = (int)((__float_as_uint(m) >> 23) & 0xFFu);
    int cand = st.S + e - 127;
    int snb = dpp_i<0x138>(st.S);
    if (lane == 0) snb = -(1 << 28);
    int snew = max(cand, snb);
    int k = st.S - snew;
    st.A0 = ldexpf(st.A0, k);
    st.A1 = ldexpf(st.A1, k);
    st.A2 = ldexpf(st.A2, k);
    st.A3 = ldexpf(st.A3, k);
    st.S = snew;
    st.D = min(dpp_i<0x138>(snew) - snew, 60);
}

__device__ __forceinline__ void step(ScanState& st, float e0, float e1, float e2, float e3) {
    float sh = ldexpf(dpp_f<0x138>(st.A3), st.D);
    sh = fminf(sh, 1.125899906842624e15f);         // 2^50; fminf absorbs inf
    float t0 = st.A0 + sh;
    float t1 = st.A1 + st.A0;
    float t2 = st.A2 + st.A1;
    float t3 = st.A3 + st.A2;
    st.A0 = e0 * t0; st.A1 = e1 * t1; st.A2 = e2 * t2; st.A3 = e3 * t3;
}

// ---- backward core: beta^T <- beta^T M_t; cross-lane term from lane l+1 via 0x130 ----
__device__ __forceinline__ void brenorm(ScanState& st) {
    float m = fmaxf(fmaxf(st.A0, st.A1), fmaxf(st.A2, st.A3));
    int e = (int)((__float_as_uint(m) >> 23) & 0xFFu);
    int cand = st.S + e - 127;
    int snb = dpp_i<0x130>(st.S);                  // lane63 gets 0 (junk side, harmless)
    int snew = max(cand, snb);
    int k = st.S - snew;
    st.A0 = ldexpf(st.A0, k);
    st.A1 = ldexpf(st.A1, k);
    st.A2 = ldexpf(st.A2, k);
    st.A3 = ldexpf(st.A3, k);
    st.S = snew;
    st.D = min(dpp_i<0x130>(snew) - snew, 60);
}

__device__ __forceinline__ void bstep(ScanState& st, float e0, float e1, float e2, float e3) {
    // newB_r = E_r B_r + E_{r+1} B_{r+1}; r=3 cross term = (E0 B0) of lane l+1,
    // built from dpp(e0) (off the serial chain) and dpp(B0).
    float e4s = fminf(ldexpf(dpp_f<0x130>(e0), st.D), 1.125899906842624e15f);
    float b0n = dpp_f<0x130>(st.A0);
    float g0 = e0 * st.A0, g1 = e1 * st.A1, g2 = e2 * st.A2, g3 = e3 * st.A3;
    st.A0 = g0 + g1; st.A1 = g1 + g2; st.A2 = g2 + g3; st.A3 = g3 + e4s * b0n;
}

__device__ __forceinline__ ScanState scan_init(const float* in, const int* tgt, int lane, int b) {
    float v0 = in[b * 64 + (tgt[b * U_DIM] & 63)];
    ScanState st;
    st.A0 = (lane == 0) ? hw_exp2(v0 * LOG2E) : 0.0f;
    st.A1 = 0.0f; st.A2 = 0.0f; st.A3 = 0.0f;
    st.S = 0; st.D = 0;
    return st;
}

#define LO(x) __uint_as_float((x) << 16)
#define HI(x) __uint_as_float((x) & 0xFFFF0000u)

// Meet-in-the-middle scan: block b has wave0 = forward (t=1..2000), wave1 = backward
// (t=3999..2001); junction dot-product + wave-lse in-block.
__global__ __launch_bounds__(128, 1) void scan2_kernel(const float* __restrict__ in,
                                                       const int* __restrict__ tgt,
                                                       const unsigned* __restrict__ eg,
                                                       float* __restrict__ out) {
    __shared__ float jb0[64], jb1[64], jb2[64], jb3[64];
    __shared__ int jsb[64];
    const int lane = threadIdx.x & 63;
    const int wv = threadIdx.x >> 6;
    const int b = blockIdx.x;
    const int lidx = (lane < 50) ? lane : 49;
    const char* egb = (const char*)eg + (size_t)b * PB_BYTES;

    ScanState st;
    if (wv == 1) {
        // ---------- backward: beta = e_199; pairs 1999 down to 1000(hi only) ----------
        st.A0 = 0.0f; st.A1 = 0.0f; st.A2 = 0.0f;
        st.A3 = (lane == 49) ? 1.0f : 0.0f;
        st.S = 0; st.D = 0;
        int off = 1999 * 800 + lidx * 16;
        uint4 wb[NSLOT];
        #pragma unroll
        for (int j = 0; j < NSLOT; ++j) { wb[j] = *(const uint4*)(egb + off); off -= 800; }
        for (int k = 0; k < 49; ++k) {
            #pragma unroll
            for (int j = 0; j < NSLOT; ++j) {
                if ((j & 3) == 0) brenorm(st);
                uint4 w = wb[j];
                wb[j] = *(const uint4*)(egb + off); off -= 800;
                bstep(st, LO(w.z), HI(w.z), LO(w.w), HI(w.w));   // t = 2p+1 first
                bstep(st, LO(w.x), HI(w.x), LO(w.y), HI(w.y));   // then t = 2p
            }
        }
        #pragma unroll
        for (int j = 0; j < NSLOT; ++j) {      // pairs 1019..1001 full, 1000 hi-only
            if ((j & 3) == 0) brenorm(st);
            uint4 w = wb[j];
            bstep(st, LO(w.z), HI(w.z), LO(w.w), HI(w.w));
            if (j < NSLOT - 1) bstep(st, LO(w.x), HI(w.x), LO(w.y), HI(w.y));
        }
        brenorm(st);
        jb0[lane] = st.A0; jb1[lane] = st.A1; jb2[lane] = st.A2; jb3[lane] = st.A3;
        jsb[lane] = st.S;
    } else {
        // ---------- forward: alpha_0 -> t=1 (pair0 hi) -> pairs 1..999 -> pair1000 lo ----------
        st = scan_init(in, tgt, lane, b);
        int off = 800 + lidx * 16;
        uint4 wb[NSLOT];
        #pragma unroll
        for (int j = 0; j < NSLOT; ++j) { wb[j] = *(const uint4*)(egb + off); off += 800; }
        uint2 h0 = *(const uint2*)(egb + lidx * 16 + 8);
        step(st, LO(h0.x), HI(h0.x), LO(h0.y), HI(h0.y));        // t = 1
        for (int k = 0; k < 49; ++k) {
            #pragma unroll
            for (int j = 0; j < NSLOT; ++j) {
                if ((j & 3) == 0) renorm(st, lane);
                uint4 w = wb[j];
                wb[j] = *(const uint4*)(egb + off); off += 800;
                step(st, LO(w.x), HI(w.x), LO(w.y), HI(w.y));    // t = 2p
                step(st, LO(w.z), HI(w.z), LO(w.w), HI(w.w));    // t = 2p+1
            }
        }
        #pragma unroll
        for (int j = 0; j < NSLOT; ++j) {      // pairs 981..999 full, 1000 lo-only
            if ((j & 3) == 0) renorm(st, lane);
            uint4 w = wb[j];
            step(st, LO(w.x), HI(w.x), LO(w.y), HI(w.y));
            if (j < NSLOT - 1) step(st, LO(w.z), HI(w.z), LO(w.w), HI(w.w));
        }
        renorm(st, lane);
    }
    __syncthreads();
    if (wv == 0) {
        // junction: log2( sum_u alpha_2000[u] * beta_2001[u] )
        float d = st.A0 * jb0[lane] + st.A1 * jb1[lane]
                + st.A2 * jb2[lane] + st.A3 * jb3[lane];
        float ll = (lane < 50) ? hw_log2(fmaxf(d, 1e-38f)) + (float)(st.S + jsb[lane])
                               : -1e30f;
        float mx = ll;
        #pragma unroll
        for (int o = 32; o > 0; o >>= 1) mx = fmaxf(mx, __shfl_xor(mx, o));
        float s = (lane < 50) ? hw_exp2(ll - mx) : 0.0f;
        #pragma unroll
        for (int o = 32; o > 0; o >>= 1) s += __shfl_xor(s, o);
        if (lane == 0) atomicAdd(out, -(mx + hw_log2(s)) * (LN2 / 64.0f));
    }
}

// ---- fallback pair (no-workspace path; R7-proven forward core) ----
__global__ __launch_bounds__(256) void lse_sum_kernel(const float* __restrict__ in,
                                                      float* __restrict__ out) {
    const int lane = threadIdx.x & 63;
    const int w = threadIdx.x >> 6;
    const int wid = blockIdx.x * 4 + w;
    const int ROWS = (T_DIM * B_DIM) / 1024;
    const float* p = in + (size_t)wid * ROWS * 64 + lane;
    float acc = 0.0f;
    for (int i = 0; i < ROWS; i += 2) {
        float xa = p[(size_t)i * 64];
        float xb = p[(size_t)(i + 1) * 64];
        float ea = hw_exp2(xa * LOG2E);
        float eb = hw_exp2(xb * LOG2E);
        #pragma unroll
        for (int off = 32; off > 0; off >>= 1) {
            ea += __shfl_xor(ea, off);
            eb += __shfl_xor(eb, off);
        }
        acc += hw_log2(ea) + hw_log2(eb);
    }
    __shared__ float red[4];
    if (lane == 0) red[w] = acc;
    __syncthreads();
    if (threadIdx.x == 0)
        atomicAdd(out, (red[0] + red[1] + red[2] + red[3]) * (LN2 / 64.0f));
}

__global__ __launch_bounds__(64) void scan_fb(const float* __restrict__ in,
                                              const int* __restrict__ tgt,
                                              float* __restrict__ out) {
    const int lane = threadIdx.x;
    const int b = blockIdx.x;
    const int lidx = (lane < 50) ? lane : 49;
    int4 tg = ((const int4*)(tgt + b * U_DIM))[lidx];
    tg.x &= 63; tg.y &= 63; tg.z &= 63; tg.w &= 63;
    ScanState st = scan_init(in, tgt, lane, b);
    const char* inb = (const char*)in;
    int o0 = 16384 + b * 256 + tg.x * 4;
    int o1 = 16384 + b * 256 + tg.y * 4;
    int o2 = 16384 + b * 256 + tg.z * 4;
    int o3 = 16384 + b * 256 + tg.w * 4;
    const int m0 = 3999 * 16384 + b * 256 + tg.x * 4;
    const int m1 = m0 + (tg.y - tg.x) * 4;
    const int m2 = m0 + (tg.z - tg.x) * 4;
    const int m3 = m0 + (tg.w - tg.x) * 4;
    float f0[16], f1[16], f2[16], f3[16];
    #pragma unroll
    for (int j = 0; j < 16; ++j) {
        f0[j] = *(const float*)(inb + min(o0, m0)); o0 += 16384;
        f1[j] = *(const float*)(inb + min(o1, m1)); o1 += 16384;
        f2[j] = *(const float*)(inb + min(o2, m2)); o2 += 16384;
        f3[j] = *(const float*)(inb + min(o3, m3)); o3 += 16384;
    }
    for (int k = 0; k < 249; ++k) {
        #pragma unroll
        for (int j = 0; j < 16; ++j) {
            if (j == 0 || j == 8) renorm(st, lane);
            float e0 = hw_exp2(f0[j] * LOG2E);
            float e1 = hw_exp2(f1[j] * LOG2E);
            float e2 = hw_exp2(f2[j] * LOG2E);
            float e3 = hw_exp2(f3[j] * LOG2E);
            f0[j] = *(const float*)(inb + min(o0, m0)); o0 += 16384;
            f1[j] = *(const float*)(inb + min(o1, m1)); o1 += 16384;
            f2[j] = *(const float*)(inb + min(o2, m2)); o2 += 16384;
            f3[j] = *(const float*)(inb + min(o3, m3)); o3 += 16384;
            step(st, e0, e1, e2, e3);
        }
    }
    #pragma unroll
    for (int j = 0; j < 15; ++j) {
        if (j == 0 || j == 8) renorm(st, lane);
        float e0 = hw_exp2(f0[j] * LOG2E);
        float e1 = hw_exp2(f1[j] * LOG2E);
        float e2 = hw_exp2(f2[j] * LOG2E);
        float e3 = hw_exp2(f3[j] * LOG2E);
        step(st, e0, e1, e2, e3);
    }
    if (lane == 49) {
        float a2 = hw_log2(fmaxf(st.A3, 1e-38f)) + (float)st.S;
        atomicAdd(out, -a2 * (LN2 / 64.0f));
    }
}

extern "C" void kernel_launch(void* const* d_in, const int* in_sizes, int n_in,
                              void* d_out, int out_size, void* d_ws, size_t ws_size,
                              hipStream_t stream) {
    const float* inputs = (const float*)d_in[0];   // (T, B, C) fp32
    const int* targets = (const int*)d_in[1];      // (B, U) int32
    float* out = (float*)d_out;                    // scalar fp32

    (void)hipMemsetAsync(out, 0, sizeof(float), stream);

    const size_t eg_bytes = (size_t)B_DIM * PB_BYTES;   // 102.4 MB
    if (ws_size >= eg_bytes) {
        unsigned* eg = (unsigned*)d_ws;
        prep_kernel<<<2000, 256, 0, stream>>>(inputs, targets, eg, out);
        scan2_kernel<<<B_DIM, 128, 0, stream>>>(inputs, targets, eg, out);
    } else {
        scan_fb<<<B_DIM, 64, 0, stream>>>(inputs, targets, out);
        lse_sum_kernel<<<256, 256, 0, stream>>>(inputs, out);
    }
}